// Round 8
// baseline (5946.609 us; speedup 1.0000x reference)
//
#include <hip/hip_runtime.h>

// ---------------------------------------------------------------------------
// LanguageModel: embed -> LSTM(1024) x2 -> last-step logits(32000) -> softmax
// B=64, S=512, E=512, H=1024, G=4H=4096, V=32000
//
// Round 12 (merge both layers into one block; one barrier per step):
//  - Key insight: L0's recurrent input at step t and L1's x-projection input
//    are the SAME fragments (h1(t-1), same afrag_base). One block now owns
//    colgroup g for BOTH layers (L1 lagged 1 step): load A=h1(t-1) once,
//    use twice (A@Wh0 and A@Wx1); load A2=h2(t-2); 96 MFMAs; both EW phases
//    through the shared gx; store h1(t)+h2(t-1); publish ONE done-flag.
//    One gate + one drain + one leader chain per step (round-11 paid two,
//    coupled), one h-exchange window instead of two.
//  - 256 blocks @ 1/CU (LDS = Wh0 64K + Wh1 64K + gx + hlds = 137.5 KiB).
//    Wx1 streamed from L2 (64 KB/block/step, L2-resident).
//  - Loop t=0..512: L0 active t<512, L1 active t>=1 (lag); epilogue step
//    computes h2(511) -> hb2. Lag-2 double-buffering audited under the
//    single gate (h2 read (t&1)?hb2:hb3, write the other; parity-safe).
//  - Leader poll moved to WAVE 3: overlaps wave-0's store+drain.
// ---------------------------------------------------------------------------

#define BB 64
#define SS 512
#define EE 512
#define HH 1024
#define GG 4096
#define VV 32000

using bf16x8 = __attribute__((ext_vector_type(8))) __bf16;
using f32x4  = __attribute__((ext_vector_type(4))) float;

__device__ __forceinline__ unsigned short f2bf(float f) {
    unsigned u = __float_as_uint(f);
    unsigned r = u + 0x7FFFu + ((u >> 16) & 1u);   // RNE
    return (unsigned short)(r >> 16);
}
__device__ __forceinline__ float bf2f(unsigned short u) {
    return __uint_as_float(((unsigned)u) << 16);
}
__device__ __forceinline__ float sigm(float x) {
    return 1.0f / (1.0f + expf(-x));
}
// 16B fragment load via two agent-scope relaxed atomics (sc1 -> coherent at IF).
__device__ __forceinline__ bf16x8 ld_frag_coh(const unsigned long long* p) {
    union { unsigned long long u[2]; bf16x8 v; } x;
    x.u[0] = __hip_atomic_load(p,     __ATOMIC_RELAXED, __HIP_MEMORY_SCOPE_AGENT);
    x.u[1] = __hip_atomic_load(p + 1, __ATOMIC_RELAXED, __HIP_MEMORY_SCOPE_AGENT);
    return x.v;
}
// All-thread gate poll on a replicated go line (wave-coalesced same-address).
__device__ __forceinline__ void gate_poll(const unsigned int* p, unsigned tgt) {
    while (__hip_atomic_load(p, __ATOMIC_RELAXED, __HIP_MEMORY_SCOPE_AGENT) < tgt)
        __builtin_amdgcn_s_sleep(1);
    __builtin_amdgcn_sched_barrier(0);   // fence: no load issue hoisted above gate
}

// Packed-B layout: elem(nt, kt, lane, j) = B[kt*32 + (lane>>4)*8 + j][nt*16 + (lane&15)]
__global__ void pack_b(const float* __restrict__ B, unsigned short* __restrict__ out,
                       int KT, int N) {
    int bid = blockIdx.x;          // = nt*KT + kt
    int lane = threadIdx.x;
    int nt = bid / KT, kt = bid % KT;
    int k = kt * 32 + ((lane >> 4) << 3);
    int n = nt * 16 + (lane & 15);
    size_t base = ((size_t)bid * 64 + lane) * 8;
    #pragma unroll
    for (int j = 0; j < 8; ++j)
        out[base + j] = f2bf(B[(size_t)(k + j) * N + n]);
}

// Wh pack: colgroup g in [0,128) owns h-cols 8g..8g+7
// -> 32 gate-cols ordered n = q*8+cj (q=gate, cj=col offset), as 2 n-tiles.
// Frag id f = (g*2 + nt)*32 + kt.  (Also used for Wx1: same 1024x4096 shape.)
__global__ void pack_wh(const float* __restrict__ Wh, unsigned short* __restrict__ out) {
    int f = blockIdx.x;            // (g*2 + nt)*32 + kt ; grid 8192
    int lane = threadIdx.x;
    int kt = f & 31, nt = (f >> 5) & 1, g = f >> 6;
    int nloc = lane & 15;
    int q = nt * 2 + (nloc >> 3), cj = nloc & 7;
    int gcol = q * HH + 8 * g + cj;
    int k = kt * 32 + ((lane >> 4) << 3);
    size_t base = ((size_t)f * 64 + lane) * 8;
    #pragma unroll
    for (int j = 0; j < 8; ++j)
        out[base + j] = f2bf(Wh[(size_t)(k + j) * GG + gcol]);
}

// Embedding gather written directly in packed-A form (M=32768 rows, K=512).
// Row order r = s*64 + b  (s-major, batch innermost).
__global__ void embed_pack(const int* __restrict__ x, const float* __restrict__ tab,
                           unsigned short* __restrict__ out) {
    int bid = blockIdx.x;          // = mt*16 + kt  (KT=16)
    int lane = threadIdx.x;
    int mt = bid >> 4, kt = bid & 15;
    int m = mt * 16 + (lane & 15);            // r = s*64 + b
    int idx = x[(m & 63) * SS + (m >> 6)];    // x is [B][S]
    int kb = kt * 32 + ((lane >> 4) << 3);
    size_t base = ((size_t)bid * 64 + lane) * 8;
    const float* src = tab + (size_t)idx * EE + kb;
    #pragma unroll
    for (int j = 0; j < 8; ++j)
        out[base + j] = f2bf(src[j]);
}

// C = A@B + bias.  MODE 0: float row-major (logits).
//                  MODE 1: bf16 x4s layout out[((s*GG + col)*64 + batch)],
//                          virtual row r = s*64 + batch; block owns one s x
//                          64 cols x 64 batches = contiguous 8KB region.
template<int MODE>
__global__ __launch_bounds__(256) void gemm_bias(
    const unsigned short* __restrict__ Ap, const unsigned short* __restrict__ Bp,
    const float* __restrict__ bias, void* __restrict__ Cout, int N, int KT) {
    __shared__ unsigned short tile[64][72];   // MODE1 transpose staging (padded)
    const int tid = threadIdx.x, lane = tid & 63, w = tid >> 6;
    const int ntg = blockIdx.x * 4 + w;
    const int m0t = blockIdx.y * 4;
    const bf16x8* Av = reinterpret_cast<const bf16x8*>(Ap);
    const bf16x8* Bv = reinterpret_cast<const bf16x8*>(Bp);
    f32x4 acc[4] = {{0.f,0.f,0.f,0.f},{0.f,0.f,0.f,0.f},{0.f,0.f,0.f,0.f},{0.f,0.f,0.f,0.f}};
    for (int kt = 0; kt < KT; ++kt) {
        bf16x8 b = Bv[((size_t)ntg * KT + kt) * 64 + lane];
        #pragma unroll
        for (int mt = 0; mt < 4; ++mt) {
            bf16x8 a = Av[((size_t)(m0t + mt) * KT + kt) * 64 + lane];
            acc[mt] = __builtin_amdgcn_mfma_f32_16x16x32_bf16(a, b, acc[mt], 0, 0, 0);
        }
    }
    const int col = ntg * 16 + (lane & 15);
    const int rq = (lane >> 4) << 2;
    const float bb = bias[col];
    if (MODE == 0) {
        #pragma unroll
        for (int mt = 0; mt < 4; ++mt)
            #pragma unroll
            for (int i = 0; i < 4; ++i) {
                int row = (m0t + mt) * 16 + rq + i;
                ((float*)Cout)[(size_t)row * N + col] = acc[mt][i] + bb;
            }
    } else {
        const int cl = w * 16 + (lane & 15);            // block-local col
        #pragma unroll
        for (int mt = 0; mt < 4; ++mt)
            #pragma unroll
            for (int i = 0; i < 4; ++i)
                tile[cl][mt * 16 + rq + i] = f2bf(acc[mt][i] + bb);
        __syncthreads();
        // linear 8KB store: out element (s*GG + col0)*64 + c*64 + b
        const int c = tid >> 2, b0 = (tid & 3) << 4;
        unsigned short* dst = (unsigned short*)Cout +
            ((size_t)blockIdx.y * GG + (size_t)blockIdx.x * 64) * 64 + (size_t)tid * 16;
        const uint4* s4 = reinterpret_cast<const uint4*>(&tile[c][b0]);
        reinterpret_cast<uint4*>(dst)[0] = s4[0];
        reinterpret_cast<uint4*>(dst)[1] = s4[1];
    }
}

// Zero h0 for both layers + done flags + go replicas.
__global__ void zero_init(unsigned short* __restrict__ h0a,
                          unsigned short* __restrict__ h0b,
                          unsigned int* __restrict__ flags) {
    int i = blockIdx.x * 256 + threadIdx.x;      // grid 64 x 256
    for (int k = i; k < BB * HH; k += 64 * 256) { h0a[k] = 0; h0b[k] = 0; }
    for (int k = i; k < 9216; k += 64 * 256) flags[k] = 0;
}

// Merged two-layer persistent LSTM. Grid 256 x 256 (cooperative, 1 block/CU).
// Block b: g = b>>1 (h-colgroup, both layers), hf = b&1 (batch rows 32hf..+31).
// Per step t (t=0..SS): L0 computes h1(t) [t<SS]; L1 computes h2(t-1) [t>=1].
// A = h1(t-1) fragments, shared by L0-recurrent and L1-x-projection.
// done[hf][128] 16-u32-padded lines; go replicas at +8192 + hf*256 (16 lines).
// Go value v <=> all blocks completed steps 0..v-1.
__global__ __launch_bounds__(256, 1) void lstm_fused(
    const unsigned short* __restrict__ x4s,   // layer-0 input proj (s-major x4)
    const unsigned short* __restrict__ wh0p, const unsigned short* __restrict__ wh1p,
    const unsigned short* __restrict__ wx1p,  // pack_wh layout
    const float* __restrict__ b1,
    unsigned short* __restrict__ hb0, unsigned short* __restrict__ hb1,
    unsigned short* __restrict__ hb2, unsigned short* __restrict__ hb3,
    unsigned int* __restrict__ flags) {
    __shared__ float gx[2][32][36];                         // [khalf][n][block-row]
    __shared__ __align__(16) unsigned short hlds[32][8];    // gathered h chunks
    __shared__ __align__(16) unsigned short Blds0[64 * 64 * 8];  // 64 KB Wh0 slice
    __shared__ __align__(16) unsigned short Blds1[64 * 64 * 8];  // 64 KB Wh1 slice
    const int tid = threadIdx.x, lane = tid & 63, w = tid >> 6;
    const int g = blockIdx.x >> 1, hf = blockIdx.x & 1;
    unsigned int* done = flags + hf * 2048;                 // 128 x 16 u32
    unsigned int* goL  = flags + 8192 + hf * 256;           // 16 replica lines
    const int rep = (g & 15) * 16;

    // ---- stage Wh0 + Wh1 colgroup slices (64 KB each) into LDS, once ----
    {
        const uint4* s0 = reinterpret_cast<const uint4*>(wh0p) + (size_t)g * 4096;
        const uint4* s1 = reinterpret_cast<const uint4*>(wh1p) + (size_t)g * 4096;
        uint4* d0 = reinterpret_cast<uint4*>(Blds0);
        uint4* d1 = reinterpret_cast<uint4*>(Blds1);
        #pragma unroll
        for (int i = 0; i < 16; ++i) {
            d0[i * 256 + tid] = s0[i * 256 + tid];
            d1[i * 256 + tid] = s1[i * 256 + tid];
        }
    }
    __syncthreads();
    const bf16x8* Bl0 = reinterpret_cast<const bf16x8*>(Blds0);
    const bf16x8* Bl1 = reinterpret_cast<const bf16x8*>(Blds1);
    const bf16x8* Wx  = reinterpret_cast<const bf16x8*>(wx1p);

    const int msub = w & 1, kh = w >> 1;
    const int kh16 = kh * 16;
    const int nloc = lane & 15;
    const int cj = nloc & 7;
    const int q0 = nloc >> 3;                               // gate idx for nt=0
    const int gq0 = q0 * HH + 8 * g + cj;                   // nt=0 gate col
    const int gq1 = (2 + q0) * HH + 8 * g + cj;             // nt=1 gate col
    const int rbase = msub * 16 + ((lane >> 4) << 2);       // block-local row base
    const size_t afrag_base = ((size_t)(2 * hf + msub) * 32 + (size_t)kh * 16) * 64 + lane;
    const int row_l = tid >> 3, cj2 = tid & 7;
    float c0 = 0.f, c1 = 0.f;
    const float bb0 = b1[gq0], bb1 = b1[gq1];

    // prologue: x4s prefetch for t=0
    ushort4 xv0 = {0, 0, 0, 0}, xv1 = {0, 0, 0, 0};
    if (kh == 0) {
        xv0 = *reinterpret_cast<const ushort4*>(x4s + ((size_t)gq0) * 64 + 32 * hf + rbase);
        xv1 = *reinterpret_cast<const ushort4*>(x4s + ((size_t)gq1) * 64 + 32 * hf + rbase);
    }

    #pragma unroll 1
    for (int t = 0; t <= SS; ++t) {
        // ---- single gate: all blocks completed step t-1 ----
        if (t > 0)
            gate_poll(&goL[rep], (unsigned)t);

        // ---- fragment loads: A = h1(t-1) (always), A2 = h2(t-2) (t>=1) ----
        const unsigned long long* hv1 =
            reinterpret_cast<const unsigned long long*>((t & 1) ? hb1 : hb0);
        bf16x8 A[16];
        #pragma unroll
        for (int k = 0; k < 16; ++k)
            A[k] = ld_frag_coh(hv1 + (afrag_base + (size_t)k * 64) * 2);

        bf16x8 A2[16];
        if (t >= 1) {
            const unsigned long long* hv2 =
                reinterpret_cast<const unsigned long long*>((t & 1) ? hb2 : hb3);
            #pragma unroll
            for (int k = 0; k < 16; ++k)
                A2[k] = ld_frag_coh(hv2 + (afrag_base + (size_t)k * 64) * 2);
        }

        // ---- MFMAs: L0 recurrent (A@Wh0), L1 x-proj (A@Wx1), L1 rec (A2@Wh1)
        f32x4 a00 = {0.f,0.f,0.f,0.f}, a01 = {0.f,0.f,0.f,0.f};
        f32x4 a10 = {0.f,0.f,0.f,0.f}, a11 = {0.f,0.f,0.f,0.f};
        if (t < SS) {
            #pragma unroll
            for (int k = 0; k < 16; ++k) {
                a00 = __builtin_amdgcn_mfma_f32_16x16x32_bf16(
                    A[k], Bl0[(kh16 + k) * 64 + lane], a00, 0, 0, 0);
                a01 = __builtin_amdgcn_mfma_f32_16x16x32_bf16(
                    A[k], Bl0[(32 + kh16 + k) * 64 + lane], a01, 0, 0, 0);
            }
        }
        if (t >= 1) {
            {
                bf16x8 BXa[8], BXb[8];
                #pragma unroll
                for (int j = 0; j < 8; ++j) {
                    BXa[j] = Wx[((size_t)(g * 64 + kh16 + j)) * 64 + lane];
                    BXb[j] = Wx[((size_t)(g * 64 + 32 + kh16 + j)) * 64 + lane];
                }
                #pragma unroll
                for (int j = 0; j < 8; ++j) {
                    a10 = __builtin_amdgcn_mfma_f32_16x16x32_bf16(A[j], BXa[j], a10, 0, 0, 0);
                    a11 = __builtin_amdgcn_mfma_f32_16x16x32_bf16(A[j], BXb[j], a11, 0, 0, 0);
                }
                #pragma unroll
                for (int j = 0; j < 8; ++j) {
                    BXa[j] = Wx[((size_t)(g * 64 + kh16 + 8 + j)) * 64 + lane];
                    BXb[j] = Wx[((size_t)(g * 64 + 32 + kh16 + 8 + j)) * 64 + lane];
                }
                #pragma unroll
                for (int j = 0; j < 8; ++j) {
                    a10 = __builtin_amdgcn_mfma_f32_16x16x32_bf16(A[8 + j], BXa[j], a10, 0, 0, 0);
                    a11 = __builtin_amdgcn_mfma_f32_16x16x32_bf16(A[8 + j], BXb[j], a11, 0, 0, 0);
                }
            }
            #pragma unroll
            for (int k = 0; k < 16; ++k) {
                a10 = __builtin_amdgcn_mfma_f32_16x16x32_bf16(
                    A2[k], Bl1[(kh16 + k) * 64 + lane], a10, 0, 0, 0);
                a11 = __builtin_amdgcn_mfma_f32_16x16x32_bf16(
                    A2[k], Bl1[(32 + kh16 + k) * 64 + lane], a11, 0, 0, 0);
            }
        }

        // ---- EW phase 0: layer-0 gates -> h1(t) ----
        if (t < SS) {
            if (kh == 0) {
                gx[0][nloc][rbase + 0] = a00[0] + bf2f(xv0.x);
                gx[0][nloc][rbase + 1] = a00[1] + bf2f(xv0.y);
                gx[0][nloc][rbase + 2] = a00[2] + bf2f(xv0.z);
                gx[0][nloc][rbase + 3] = a00[3] + bf2f(xv0.w);
                gx[0][16 + nloc][rbase + 0] = a01[0] + bf2f(xv1.x);
                gx[0][16 + nloc][rbase + 1] = a01[1] + bf2f(xv1.y);
                gx[0][16 + nloc][rbase + 2] = a01[2] + bf2f(xv1.z);
                gx[0][16 + nloc][rbase + 3] = a01[3] + bf2f(xv1.w);
            } else {
                gx[1][nloc][rbase + 0] = a00[0];
                gx[1][nloc][rbase + 1] = a00[1];
                gx[1][nloc][rbase + 2] = a00[2];
                gx[1][nloc][rbase + 3] = a00[3];
                gx[1][16 + nloc][rbase + 0] = a01[0];
                gx[1][16 + nloc][rbase + 1] = a01[1];
                gx[1][16 + nloc][rbase + 2] = a01[2];
                gx[1][16 + nloc][rbase + 3] = a01[3];
            }
            __syncthreads();
            float gi = gx[0][0 * 8 + cj2][row_l] + gx[1][0 * 8 + cj2][row_l];
            float gf = gx[0][1 * 8 + cj2][row_l] + gx[1][1 * 8 + cj2][row_l];
            float gg = gx[0][2 * 8 + cj2][row_l] + gx[1][2 * 8 + cj2][row_l];
            float go = gx[0][3 * 8 + cj2][row_l] + gx[1][3 * 8 + cj2][row_l];
            float cn = sigm(gf) * c0 + sigm(gi) * tanhf(gg);
            c0 = cn;
            hlds[row_l][cj2] = f2bf(sigm(go) * tanhf(cn));
            __syncthreads();
            // wave 0: gather + coherent h1(t) store (concurrent with gx(L1) writes)
            if (tid < 32) {
                union { uint4 v; unsigned long long u[2]; } cv;
                cv.v = *reinterpret_cast<const uint4*>(&hlds[tid][0]);
                const int m = 32 * hf + tid;
                unsigned short* hout1 = (t & 1) ? hb0 : hb1;
                unsigned long long* dst = reinterpret_cast<unsigned long long*>(
                    hout1 + (((size_t)(m >> 4) * 32 + (g >> 2)) * 64 + (g & 3) * 16 + (m & 15)) * 8);
                __hip_atomic_store(dst,     cv.u[0], __ATOMIC_RELAXED, __HIP_MEMORY_SCOPE_AGENT);
                __hip_atomic_store(dst + 1, cv.u[1], __ATOMIC_RELAXED, __HIP_MEMORY_SCOPE_AGENT);
            }
        }

        // ---- EW phase 1: layer-1 gates -> h2(t-1) ----
        if (t >= 1) {
            if (kh == 0) {
                gx[0][nloc][rbase + 0] = a10[0] + bb0;
                gx[0][nloc][rbase + 1] = a10[1] + bb0;
                gx[0][nloc][rbase + 2] = a10[2] + bb0;
                gx[0][nloc][rbase + 3] = a10[3] + bb0;
                gx[0][16 + nloc][rbase + 0] = a11[0] + bb1;
                gx[0][16 + nloc][rbase + 1] = a11[1] + bb1;
                gx[0][16 + nloc][rbase + 2] = a11[2] + bb1;
                gx[0][16 + nloc][rbase + 3] = a11[3] + bb1;
            } else {
                gx[1][nloc][rbase + 0] = a10[0];
                gx[1][nloc][rbase + 1] = a10[1];
                gx[1][nloc][rbase + 2] = a10[2];
                gx[1][nloc][rbase + 3] = a10[3];
                gx[1][16 + nloc][rbase + 0] = a11[0];
                gx[1][16 + nloc][rbase + 1] = a11[1];
                gx[1][16 + nloc][rbase + 2] = a11[2];
                gx[1][16 + nloc][rbase + 3] = a11[3];
            }
            __syncthreads();
            float gi = gx[0][0 * 8 + cj2][row_l] + gx[1][0 * 8 + cj2][row_l];
            float gf = gx[0][1 * 8 + cj2][row_l] + gx[1][1 * 8 + cj2][row_l];
            float gg = gx[0][2 * 8 + cj2][row_l] + gx[1][2 * 8 + cj2][row_l];
            float go = gx[0][3 * 8 + cj2][row_l] + gx[1][3 * 8 + cj2][row_l];
            float cn = sigm(gf) * c1 + sigm(gi) * tanhf(gg);
            c1 = cn;
            hlds[row_l][cj2] = f2bf(sigm(go) * tanhf(cn));
            __syncthreads();
            if (tid < 32) {
                union { uint4 v; unsigned long long u[2]; } cv;
                cv.v = *reinterpret_cast<const uint4*>(&hlds[tid][0]);
                const int m = 32 * hf + tid;
                unsigned short* hout2 = (t & 1) ? hb3 : hb2;   // h2(t-1), parity (t-1)&1
                unsigned long long* dst = reinterpret_cast<unsigned long long*>(
                    hout2 + (((size_t)(m >> 4) * 32 + (g >> 2)) * 64 + (g & 3) * 16 + (m & 15)) * 8);
                __hip_atomic_store(dst,     cv.u[0], __ATOMIC_RELAXED, __HIP_MEMORY_SCOPE_AGENT);
                __hip_atomic_store(dst + 1, cv.u[1], __ATOMIC_RELAXED, __HIP_MEMORY_SCOPE_AGENT);
            }
        }

        // ---- publish: one drain + one done-flag + one leader chain ----
        if (t < SS) {
            if (w == 0)
                asm volatile("s_waitcnt vmcnt(0)" ::: "memory");  // h1+h2 stores (wave 0)
            if (tid == 0)
                __hip_atomic_store(&done[g * 16], (unsigned)(t + 1),
                                   __ATOMIC_RELAXED, __HIP_MEMORY_SCOPE_AGENT);
            // leader (g==0): WAVE 3 observes 128 done-flags (overlaps wave-0 drain),
            // lanes 0-15 publish 16 go replicas
            if (g == 0 && w == 3) {
                const unsigned tgt = (unsigned)(t + 1);
                unsigned v0 = 0, v1 = 0;
                while (1) {
                    if (v0 < tgt)
                        v0 = __hip_atomic_load(&done[lane * 16], __ATOMIC_RELAXED,
                                               __HIP_MEMORY_SCOPE_AGENT);
                    if (v1 < tgt)
                        v1 = __hip_atomic_load(&done[(lane + 64) * 16], __ATOMIC_RELAXED,
                                               __HIP_MEMORY_SCOPE_AGENT);
                    if (__all((v0 >= tgt) && (v1 >= tgt))) break;
                    __builtin_amdgcn_s_sleep(1);
                }
                if (lane < 16)
                    __hip_atomic_store(&goL[lane * 16], tgt, __ATOMIC_RELAXED,
                                       __HIP_MEMORY_SCOPE_AGENT);
            }
            // off-path: next-step x4s prefetch
            if (kh == 0 && t + 1 < SS) {
                xv0 = *reinterpret_cast<const ushort4*>(
                    x4s + ((size_t)(t + 1) * GG + gq0) * 64 + 32 * hf + rbase);
                xv1 = *reinterpret_cast<const ushort4*>(
                    x4s + ((size_t)(t + 1) * GG + gq1) * 64 + 32 * hf + rbase);
            }
        }
    }
}

__global__ __launch_bounds__(256) void softmax_rows(const float* __restrict__ logits,
                                                    float* __restrict__ out) {
    __shared__ float red[256];
    int rr = blockIdx.x, tid = threadIdx.x;
    const float* L = logits + (size_t)rr * VV;
    float m = -1e30f;
    for (int i = tid; i < VV; i += 256) m = fmaxf(m, L[i]);
    red[tid] = m; __syncthreads();
    for (int s = 128; s > 0; s >>= 1) { if (tid < s) red[tid] = fmaxf(red[tid], red[tid + s]); __syncthreads(); }
    m = red[0]; __syncthreads();
    float sum = 0.f;
    for (int i = tid; i < VV; i += 256) sum += expf(L[i] - m);
    red[tid] = sum; __syncthreads();
    for (int s = 128; s > 0; s >>= 1) { if (tid < s) red[tid] += red[tid + s]; __syncthreads(); }
    float inv = 1.f / red[0];
    for (int i = tid; i < VV; i += 256) out[(size_t)rr * VV + i] = expf(L[i] - m) * inv;
}

extern "C" void kernel_launch(void* const* d_in, const int* in_sizes, int n_in,
                              void* d_out, int out_size, void* d_ws, size_t ws_size,
                              hipStream_t stream) {
    const int*   x    = (const int*)  d_in[0];
    const float* tab  = (const float*)d_in[1];
    const float* Wx0  = (const float*)d_in[2];
    const float* Wh0  = (const float*)d_in[3];
    const float* b0   = (const float*)d_in[4];
    const float* Wx1  = (const float*)d_in[5];
    const float* Wh1  = (const float*)d_in[6];
    const float* b1   = (const float*)d_in[7];
    const float* Wout = (const float*)d_in[8];
    const float* bout = (const float*)d_in[9];
    float* out = (float*)d_out;

    // ---- workspace layout (ushort units); all segments 16B-aligned ----
    unsigned short* ws    = (unsigned short*)d_ws;
    unsigned short* embA  = ws;                    // 16,777,216
    unsigned short* wx0p  = embA  + 16777216;      //  2,097,152
    unsigned short* wh0p  = wx0p  + 2097152;       //  4,194,304
    unsigned short* wx1p  = wh0p  + 4194304;       //  4,194,304 (pack_wh layout)
    unsigned short* wh1p  = wx1p  + 4194304;       //  4,194,304
    unsigned short* woutp = wh1p  + 4194304;       // 32,768,000
    unsigned short* x4s   = woutp + 32768000;      // 134,217,728 (layer-0 only)
    unsigned short* hb0   = x4s   + 134217728;     // 65,536  (h1, parity A)
    unsigned short* hb1   = hb0   + 65536;         // 65,536  (h1, parity B)
    unsigned short* hb2   = hb1   + 65536;         // 65,536  (h2, odd steps)
    unsigned short* hb3   = hb2   + 65536;         // 65,536  (h2, even steps)
    float* logits = (float*)(hb3 + 65536);         // 2,048,000 f32
    unsigned int* flags = (unsigned int*)(logits + 2048000);  // done + go replicas
    // total ~440 MB

    // ---- weight packing ----
    pack_b <<<256 * 16, 64, 0, stream>>>(Wx0, wx0p, 16, GG);
    pack_wh<<<8192, 64, 0, stream>>>(Wh0, wh0p);
    pack_wh<<<8192, 64, 0, stream>>>(Wx1, wx1p);   // per-colgroup slice layout
    pack_wh<<<8192, 64, 0, stream>>>(Wh1, wh1p);
    pack_b <<<2000 * 32, 64, 0, stream>>>(Wout, woutp, 32, VV);

    // ---- h0 + flag init ----
    zero_init<<<64, 256, 0, stream>>>(hb0, hb2, flags);

    // ---- embedding + layer-0 input projection ----
    embed_pack<<<32768, 64, 0, stream>>>(x, tab, embA);
    gemm_bias<1><<<dim3(GG / 64, 32768 / 64), 256, 0, stream>>>(embA, wx0p, b0, x4s, GG, EE / 32);

    // ---- merged two-layer recurrence (persistent cooperative, 256 blocks) ----
    {
        const unsigned short* a0 = x4s;
        const unsigned short* a1 = wh0p; const unsigned short* a2 = wh1p;
        const unsigned short* a3 = wx1p; const float* a4 = b1;
        unsigned short *a5 = hb0, *a6 = hb1, *a7 = hb2, *a8 = hb3;
        unsigned int* a9 = flags;
        void* args[] = {&a0, &a1, &a2, &a3, &a4, &a5, &a6, &a7, &a8, &a9};
        hipLaunchCooperativeKernel((const void*)lstm_fused, dim3(256), dim3(256),
                                   args, 0, stream);
    }
    // h2(511) (s=511 odd) lands in hb2

    // ---- logits (last timestep) + softmax ----
    gemm_bias<0><<<dim3(VV / 64, 1), 256, 0, stream>>>(hb2, woutp, bout, logits, VV, HH / 32);
    softmax_rows<<<64, 256, 0, stream>>>(logits, out);
}

// Round 9
// 3531.470 us; speedup vs baseline: 1.6839x; 1.6839x over previous
//
#include <hip/hip_runtime.h>

// ---------------------------------------------------------------------------
// LanguageModel: embed -> LSTM(1024) x2 -> last-step logits(32000) -> softmax
// B=64, S=512, E=512, H=1024, G=4H=4096, V=32000
//
// Round 13 (revert round-12 merge; fuse L0 x-projection on the fly):
//  - Round-12 lesson: merging both layers into one block serialized the two
//    bodies (step = sum, 10.25us) and halved occupancy. The round-11
//    pipeline (separate L0/L1 blocks, 2/CU, step = max ~= 6.3us) is right.
//    Reverted to round-11 EXACTLY for the recurrence + sync structure.
//  - New: L0 computes its input projection ON THE FLY like L1 does:
//    prefetch 8 embA fragments (static, plain loads, publish-tail = off-path)
//    and run 16 x-proj MFMAs BEFORE the gate. L0 waits on the slower L1
//    (oth-gate) with ~2us slack/step, so this work is free. b0 added as EW
//    constants. Removes the gemm_bias<1> dispatch (~250us) and the 268MB
//    x4s write+read HBM round trip. No intermediate bf16 rounding of x4.
//  - Wx0 packed per-colgroup via generalized pack_whk (KT=16).
// ---------------------------------------------------------------------------

#define BB 64
#define SS 512
#define EE 512
#define HH 1024
#define GG 4096
#define VV 32000

using bf16x8 = __attribute__((ext_vector_type(8))) __bf16;
using f32x4  = __attribute__((ext_vector_type(4))) float;

__device__ __forceinline__ unsigned short f2bf(float f) {
    unsigned u = __float_as_uint(f);
    unsigned r = u + 0x7FFFu + ((u >> 16) & 1u);   // RNE
    return (unsigned short)(r >> 16);
}
__device__ __forceinline__ float bf2f(unsigned short u) {
    return __uint_as_float(((unsigned)u) << 16);
}
__device__ __forceinline__ float sigm(float x) {
    return 1.0f / (1.0f + expf(-x));
}
// 16B fragment load via two agent-scope relaxed atomics (sc1 -> coherent at IF).
__device__ __forceinline__ bf16x8 ld_frag_coh(const unsigned long long* p) {
    union { unsigned long long u[2]; bf16x8 v; } x;
    x.u[0] = __hip_atomic_load(p,     __ATOMIC_RELAXED, __HIP_MEMORY_SCOPE_AGENT);
    x.u[1] = __hip_atomic_load(p + 1, __ATOMIC_RELAXED, __HIP_MEMORY_SCOPE_AGENT);
    return x.v;
}
// All-thread gate poll on a replicated go line (wave-coalesced same-address).
__device__ __forceinline__ void gate_poll(const unsigned int* p, unsigned tgt) {
    while (__hip_atomic_load(p, __ATOMIC_RELAXED, __HIP_MEMORY_SCOPE_AGENT) < tgt)
        __builtin_amdgcn_s_sleep(1);
    __builtin_amdgcn_sched_barrier(0);   // fence: no load issue hoisted above gate
}

// Packed-B layout: elem(nt, kt, lane, j) = B[kt*32 + (lane>>4)*8 + j][nt*16 + (lane&15)]
__global__ void pack_b(const float* __restrict__ B, unsigned short* __restrict__ out,
                       int KT, int N) {
    int bid = blockIdx.x;          // = nt*KT + kt
    int lane = threadIdx.x;
    int nt = bid / KT, kt = bid % KT;
    int k = kt * 32 + ((lane >> 4) << 3);
    int n = nt * 16 + (lane & 15);
    size_t base = ((size_t)bid * 64 + lane) * 8;
    #pragma unroll
    for (int j = 0; j < 8; ++j)
        out[base + j] = f2bf(B[(size_t)(k + j) * N + n]);
}

// Per-colgroup pack for [K x 4096] weights: colgroup g owns h-cols 8g..8g+7
// -> 32 gate-cols ordered n = q*8+cj (q=gate, cj=col offset), as 2 n-tiles.
// Frag id f = (g*2 + nt)*KT + kt ; grid 128*2*KT. (Wh: KT=32, Wx0: KT=16.)
__global__ void pack_whk(const float* __restrict__ W, unsigned short* __restrict__ out,
                         int KT) {
    int f = blockIdx.x;
    int lane = threadIdx.x;
    int kt = f % KT, r = f / KT;
    int nt = r & 1, g = r >> 1;
    int nloc = lane & 15;
    int q = nt * 2 + (nloc >> 3), cj = nloc & 7;
    int gcol = q * HH + 8 * g + cj;
    int k = kt * 32 + ((lane >> 4) << 3);
    size_t base = ((size_t)f * 64 + lane) * 8;
    #pragma unroll
    for (int j = 0; j < 8; ++j)
        out[base + j] = f2bf(W[(size_t)(k + j) * GG + gcol]);
}

// Embedding gather written directly in packed-A form (M=32768 rows, K=512).
// Row order r = s*64 + b  (s-major, batch innermost).
__global__ void embed_pack(const int* __restrict__ x, const float* __restrict__ tab,
                           unsigned short* __restrict__ out) {
    int bid = blockIdx.x;          // = mt*16 + kt  (KT=16)
    int lane = threadIdx.x;
    int mt = bid >> 4, kt = bid & 15;
    int m = mt * 16 + (lane & 15);            // r = s*64 + b
    int idx = x[(m & 63) * SS + (m >> 6)];    // x is [B][S]
    int kb = kt * 32 + ((lane >> 4) << 3);
    size_t base = ((size_t)bid * 64 + lane) * 8;
    const float* src = tab + (size_t)idx * EE + kb;
    #pragma unroll
    for (int j = 0; j < 8; ++j)
        out[base + j] = f2bf(src[j]);
}

// C = A@B + bias, float row-major (logits).
__global__ __launch_bounds__(256) void gemm_bias(
    const unsigned short* __restrict__ Ap, const unsigned short* __restrict__ Bp,
    const float* __restrict__ bias, float* __restrict__ Cout, int N, int KT) {
    const int tid = threadIdx.x, lane = tid & 63, w = tid >> 6;
    const int ntg = blockIdx.x * 4 + w;
    const int m0t = blockIdx.y * 4;
    const bf16x8* Av = reinterpret_cast<const bf16x8*>(Ap);
    const bf16x8* Bv = reinterpret_cast<const bf16x8*>(Bp);
    f32x4 acc[4] = {{0.f,0.f,0.f,0.f},{0.f,0.f,0.f,0.f},{0.f,0.f,0.f,0.f},{0.f,0.f,0.f,0.f}};
    for (int kt = 0; kt < KT; ++kt) {
        bf16x8 b = Bv[((size_t)ntg * KT + kt) * 64 + lane];
        #pragma unroll
        for (int mt = 0; mt < 4; ++mt) {
            bf16x8 a = Av[((size_t)(m0t + mt) * KT + kt) * 64 + lane];
            acc[mt] = __builtin_amdgcn_mfma_f32_16x16x32_bf16(a, b, acc[mt], 0, 0, 0);
        }
    }
    const int col = ntg * 16 + (lane & 15);
    const int rq = (lane >> 4) << 2;
    const float bb = bias[col];
    #pragma unroll
    for (int mt = 0; mt < 4; ++mt)
        #pragma unroll
        for (int i = 0; i < 4; ++i) {
            int row = (m0t + mt) * 16 + rq + i;
            Cout[(size_t)row * N + col] = acc[mt][i] + bb;
        }
}

// Zero h0 for both layers + done flags (8192) + go replicas (1024).
__global__ void zero_init(unsigned short* __restrict__ h0a,
                          unsigned short* __restrict__ h0b,
                          unsigned int* __restrict__ flags) {
    int i = blockIdx.x * 256 + threadIdx.x;      // grid 64 x 256
    for (int k = i; k < BB * HH; k += 64 * 256) { h0a[k] = 0; h0b[k] = 0; }
    for (int k = i; k < 9216; k += 64 * 256) flags[k] = 0;
}

// Fused two-layer persistent LSTM. Grid 512 x 256 (cooperative, 2 blocks/CU).
// Block b: L = b>=256, inner = b&255, g = inner>>1 (h-colgroup), hf = inner&1.
// done[L][hf][128] 16-u32-padded lines; go replicas at +8192:
// go[(L*2+hf)][r] for r in [0,16), each a 16-u32 line. Block polls r = g&15.
// Go value v <=> that layer+domain completed steps 0..v-1.
__global__ __launch_bounds__(256, 2) void lstm_fused(
    const unsigned short* __restrict__ embA,  // packed-A embedding (static)
    const unsigned short* __restrict__ wx0p,  // pack_whk KT=16 layout
    const unsigned short* __restrict__ wh0p, const unsigned short* __restrict__ wh1p,
    const unsigned short* __restrict__ wx1p,  // pack_whk KT=32 layout
    const float* __restrict__ b0c, const float* __restrict__ b1c,
    unsigned short* __restrict__ hb0, unsigned short* __restrict__ hb1,
    unsigned short* __restrict__ hb2, unsigned short* __restrict__ hb3,
    unsigned int* __restrict__ flags) {
    __shared__ float gx[2][32][36];                         // [khalf][n][block-row]
    __shared__ __align__(16) unsigned short hlds[32][8];    // gathered h chunks
    __shared__ __align__(16) unsigned short Blds[64 * 64 * 8];  // 64 KB Wh slice
    const int tid = threadIdx.x, lane = tid & 63, w = tid >> 6;
    const int L = (blockIdx.x >= 256) ? 1 : 0;
    const int inner = blockIdx.x & 255;
    const int g = inner >> 1, hf = inner & 1;
    unsigned int* done   = flags + L * 4096 + hf * 2048;            // 128 x 16
    unsigned int* go_own = flags + 8192 + (L * 2 + hf) * 256;       // 16 lines
    unsigned int* go_oth = flags + 8192 + ((1 - L) * 2 + hf) * 256;
    const int rep = (g & 15) * 16;                                  // replica line

    // ---- stage this colgroup's Wh slice (64 KB) into LDS, once ----
    {
        const uint4* src = reinterpret_cast<const uint4*>(L ? wh1p : wh0p) + (size_t)g * 4096;
        uint4* dst = reinterpret_cast<uint4*>(Blds);
        #pragma unroll
        for (int i = 0; i < 16; ++i)
            dst[i * 256 + tid] = src[i * 256 + tid];
    }
    __syncthreads();
    const bf16x8* Bl = reinterpret_cast<const bf16x8*>(Blds);

    const int msub = w & 1, kh = w >> 1;
    const int kh16 = kh * 16;
    const int nloc = lane & 15;
    const int cj = nloc & 7;
    const int q0 = nloc >> 3;                               // gate idx for nt=0
    const int gq0 = q0 * HH + 8 * g + cj;                   // nt=0 gate col
    const int gq1 = (2 + q0) * HH + 8 * g + cj;             // nt=1 gate col
    const int rbase = msub * 16 + ((lane >> 4) << 2);       // block-local row base
    const size_t afrag_base = ((size_t)(2 * hf + msub) * 32 + (size_t)kh * 16) * 64 + lane;
    const int row_l = tid >> 3, cj2 = tid & 7;
    float c = 0.f;

    if (L == 0) {
        // =================== layer 0 (on-the-fly x-projection) ===============
        const float bb0 = b0c[gq0], bb1 = b0c[gq1];
        const bf16x8* Wx0v = reinterpret_cast<const bf16x8*>(wx0p);
        const bf16x8* Ev   = reinterpret_cast<const bf16x8*>(embA);
        const int kh8 = kh * 8;
        // prologue: A_emb(0) prefetch (8 frags, K=512 half per wave)
        bf16x8 Ae[8];
        {
            const int mt = 2 * hf + msub;   // t=0: mt = 4*0 + 2hf + msub
            #pragma unroll
            for (int j = 0; j < 8; ++j)
                Ae[j] = Ev[((size_t)(mt * 16 + kh8 + j)) * 64 + lane];
        }
        #pragma unroll 1
        for (int t = 0; t < SS; ++t) {
            // ---- pre-gate x-projection: emb(t) @ Wx0-slice (off-path; L0
            //      waits on the slower L1 via oth-gate, so this is free) ----
            f32x4 acc0 = {0.f, 0.f, 0.f, 0.f}, acc1 = {0.f, 0.f, 0.f, 0.f};
            #pragma unroll
            for (int j = 0; j < 8; ++j) {
                bf16x8 BXa = Wx0v[((size_t)(g * 32 + kh8 + j)) * 64 + lane];
                bf16x8 BXb = Wx0v[((size_t)(g * 32 + 16 + kh8 + j)) * 64 + lane];
                acc0 = __builtin_amdgcn_mfma_f32_16x16x32_bf16(Ae[j], BXa, acc0, 0, 0, 0);
                acc1 = __builtin_amdgcn_mfma_f32_16x16x32_bf16(Ae[j], BXb, acc1, 0, 0, 0);
            }
            // gates (all-thread, replicated lines): own done t-1; L1 done t-2
            if (t > 0) {
                gate_poll(&go_own[rep], (unsigned)t);
                if (t >= 2) gate_poll(&go_oth[rep], (unsigned)(t - 1));
            }
            const unsigned long long* hv =
                reinterpret_cast<const unsigned long long*>((t & 1) ? hb1 : hb0);
            unsigned short* hout = (t & 1) ? hb0 : hb1;

            bf16x8 A[16];
            #pragma unroll
            for (int k = 0; k < 16; ++k)
                A[k] = ld_frag_coh(hv + (afrag_base + (size_t)k * 64) * 2);

            #pragma unroll
            for (int k = 0; k < 16; ++k) {
                acc0 = __builtin_amdgcn_mfma_f32_16x16x32_bf16(
                    A[k], Bl[(kh16 + k) * 64 + lane], acc0, 0, 0, 0);
                acc1 = __builtin_amdgcn_mfma_f32_16x16x32_bf16(
                    A[k], Bl[(32 + kh16 + k) * 64 + lane], acc1, 0, 0, 0);
            }
            if (kh == 0) {
                gx[0][nloc][rbase + 0] = acc0[0] + bb0;
                gx[0][nloc][rbase + 1] = acc0[1] + bb0;
                gx[0][nloc][rbase + 2] = acc0[2] + bb0;
                gx[0][nloc][rbase + 3] = acc0[3] + bb0;
                gx[0][16 + nloc][rbase + 0] = acc1[0] + bb1;
                gx[0][16 + nloc][rbase + 1] = acc1[1] + bb1;
                gx[0][16 + nloc][rbase + 2] = acc1[2] + bb1;
                gx[0][16 + nloc][rbase + 3] = acc1[3] + bb1;
            } else {
                gx[1][nloc][rbase + 0] = acc0[0];
                gx[1][nloc][rbase + 1] = acc0[1];
                gx[1][nloc][rbase + 2] = acc0[2];
                gx[1][nloc][rbase + 3] = acc0[3];
                gx[1][16 + nloc][rbase + 0] = acc1[0];
                gx[1][16 + nloc][rbase + 1] = acc1[1];
                gx[1][16 + nloc][rbase + 2] = acc1[2];
                gx[1][16 + nloc][rbase + 3] = acc1[3];
            }
            __syncthreads();

            float gi = gx[0][0 * 8 + cj2][row_l] + gx[1][0 * 8 + cj2][row_l];
            float gf = gx[0][1 * 8 + cj2][row_l] + gx[1][1 * 8 + cj2][row_l];
            float gg = gx[0][2 * 8 + cj2][row_l] + gx[1][2 * 8 + cj2][row_l];
            float go = gx[0][3 * 8 + cj2][row_l] + gx[1][3 * 8 + cj2][row_l];
            float cn = sigm(gf) * c + sigm(gi) * tanhf(gg);
            c = cn;
            hlds[row_l][cj2] = f2bf(sigm(go) * tanhf(cn));
            __syncthreads();

            if (tid < 32) {
                union { uint4 v; unsigned long long u[2]; } cv;
                cv.v = *reinterpret_cast<const uint4*>(&hlds[tid][0]);
                const int m = 32 * hf + tid;
                unsigned long long* dst = reinterpret_cast<unsigned long long*>(
                    hout + (((size_t)(m >> 4) * 32 + (g >> 2)) * 64 + (g & 3) * 16 + (m & 15)) * 8);
                __hip_atomic_store(dst,     cv.u[0], __ATOMIC_RELAXED, __HIP_MEMORY_SCOPE_AGENT);
                __hip_atomic_store(dst + 1, cv.u[1], __ATOMIC_RELAXED, __HIP_MEMORY_SCOPE_AGENT);
            }
            if (w == 0)
                asm volatile("s_waitcnt vmcnt(0)" ::: "memory");   // wave-0 stores only
            if (tid == 0)
                __hip_atomic_store(&done[g * 16], (unsigned)(t + 1),
                                   __ATOMIC_RELAXED, __HIP_MEMORY_SCOPE_AGENT);
            // off-path: next-step A_emb prefetch (static data, plain loads)
            if (t + 1 < SS) {
                const int mt1 = 4 * (t + 1) + 2 * hf + msub;
                #pragma unroll
                for (int j = 0; j < 8; ++j)
                    Ae[j] = Ev[((size_t)(mt1 * 16 + kh8 + j)) * 64 + lane];
            }
            // leader: observe 128 done-flags, publish 16 go replicas
            if (g == 0 && tid < 64) {
                const unsigned tgt = (unsigned)(t + 1);
                unsigned v0 = 0, v1 = 0;
                while (1) {
                    if (v0 < tgt)
                        v0 = __hip_atomic_load(&done[tid * 16], __ATOMIC_RELAXED,
                                               __HIP_MEMORY_SCOPE_AGENT);
                    if (v1 < tgt)
                        v1 = __hip_atomic_load(&done[(tid + 64) * 16], __ATOMIC_RELAXED,
                                               __HIP_MEMORY_SCOPE_AGENT);
                    if (__all((v0 >= tgt) && (v1 >= tgt))) break;
                    __builtin_amdgcn_s_sleep(1);
                }
                if (tid < 16)
                    __hip_atomic_store(&go_own[tid * 16], tgt, __ATOMIC_RELAXED,
                                       __HIP_MEMORY_SCOPE_AGENT);
            }
        }
    } else {
        // =================== layer 1 (lag 1; fused x-projection) =============
        const float bb0 = b1c[gq0], bb1 = b1c[gq1];
        const bf16x8* Wx = reinterpret_cast<const bf16x8*>(wx1p);
        #pragma unroll 1
        for (int t = 0; t < SS; ++t) {
            // cross-gate FIRST (steady state: already satisfied, L0 leads)
            gate_poll(&go_oth[rep], (unsigned)(t + 1));
            // issue h1(t) fragment loads immediately -- fly during own-gate
            const unsigned long long* hv1 =
                reinterpret_cast<const unsigned long long*>((t & 1) ? hb0 : hb1);
            bf16x8 A1[16];
            #pragma unroll
            for (int k = 0; k < 16; ++k)
                A1[k] = ld_frag_coh(hv1 + (afrag_base + (size_t)k * 64) * 2);

            // own-gate: all siblings completed step t-1 (h2(t-1) fully stored)
            if (t > 0)
                gate_poll(&go_own[rep], (unsigned)t);
            const unsigned long long* hv2 =
                reinterpret_cast<const unsigned long long*>((t & 1) ? hb3 : hb2);
            unsigned short* hout2 = (t & 1) ? hb2 : hb3;
            bf16x8 A2[16];
            #pragma unroll
            for (int k = 0; k < 16; ++k)
                A2[k] = ld_frag_coh(hv2 + (afrag_base + (size_t)k * 64) * 2);

            f32x4 acc0 = {0.f, 0.f, 0.f, 0.f}, acc1 = {0.f, 0.f, 0.f, 0.f};
            // x-projection first (A2's IF window hides under these MFMAs)
            {
                bf16x8 BXa[8], BXb[8];
                #pragma unroll
                for (int j = 0; j < 8; ++j) {
                    BXa[j] = Wx[((size_t)(g * 64 + kh16 + j)) * 64 + lane];
                    BXb[j] = Wx[((size_t)(g * 64 + 32 + kh16 + j)) * 64 + lane];
                }
                #pragma unroll
                for (int j = 0; j < 8; ++j) {
                    acc0 = __builtin_amdgcn_mfma_f32_16x16x32_bf16(A1[j], BXa[j], acc0, 0, 0, 0);
                    acc1 = __builtin_amdgcn_mfma_f32_16x16x32_bf16(A1[j], BXb[j], acc1, 0, 0, 0);
                }
                #pragma unroll
                for (int j = 0; j < 8; ++j) {
                    BXa[j] = Wx[((size_t)(g * 64 + kh16 + 8 + j)) * 64 + lane];
                    BXb[j] = Wx[((size_t)(g * 64 + 32 + kh16 + 8 + j)) * 64 + lane];
                }
                #pragma unroll
                for (int j = 0; j < 8; ++j) {
                    acc0 = __builtin_amdgcn_mfma_f32_16x16x32_bf16(A1[8 + j], BXa[j], acc0, 0, 0, 0);
                    acc1 = __builtin_amdgcn_mfma_f32_16x16x32_bf16(A1[8 + j], BXb[j], acc1, 0, 0, 0);
                }
            }
            // recurrent GEMM (A2 long since landed)
            #pragma unroll
            for (int k = 0; k < 16; ++k) {
                acc0 = __builtin_amdgcn_mfma_f32_16x16x32_bf16(
                    A2[k], Bl[(kh16 + k) * 64 + lane], acc0, 0, 0, 0);
                acc1 = __builtin_amdgcn_mfma_f32_16x16x32_bf16(
                    A2[k], Bl[(32 + kh16 + k) * 64 + lane], acc1, 0, 0, 0);
            }

            if (kh == 0) {
                gx[0][nloc][rbase + 0] = acc0[0] + bb0;
                gx[0][nloc][rbase + 1] = acc0[1] + bb0;
                gx[0][nloc][rbase + 2] = acc0[2] + bb0;
                gx[0][nloc][rbase + 3] = acc0[3] + bb0;
                gx[0][16 + nloc][rbase + 0] = acc1[0] + bb1;
                gx[0][16 + nloc][rbase + 1] = acc1[1] + bb1;
                gx[0][16 + nloc][rbase + 2] = acc1[2] + bb1;
                gx[0][16 + nloc][rbase + 3] = acc1[3] + bb1;
            } else {
                gx[1][nloc][rbase + 0] = acc0[0];
                gx[1][nloc][rbase + 1] = acc0[1];
                gx[1][nloc][rbase + 2] = acc0[2];
                gx[1][nloc][rbase + 3] = acc0[3];
                gx[1][16 + nloc][rbase + 0] = acc1[0];
                gx[1][16 + nloc][rbase + 1] = acc1[1];
                gx[1][16 + nloc][rbase + 2] = acc1[2];
                gx[1][16 + nloc][rbase + 3] = acc1[3];
            }
            __syncthreads();

            float gi = gx[0][0 * 8 + cj2][row_l] + gx[1][0 * 8 + cj2][row_l];
            float gf = gx[0][1 * 8 + cj2][row_l] + gx[1][1 * 8 + cj2][row_l];
            float gg = gx[0][2 * 8 + cj2][row_l] + gx[1][2 * 8 + cj2][row_l];
            float go = gx[0][3 * 8 + cj2][row_l] + gx[1][3 * 8 + cj2][row_l];
            float cn = sigm(gf) * c + sigm(gi) * tanhf(gg);
            c = cn;
            hlds[row_l][cj2] = f2bf(sigm(go) * tanhf(cn));
            __syncthreads();

            if (tid < 32) {
                union { uint4 v; unsigned long long u[2]; } cv;
                cv.v = *reinterpret_cast<const uint4*>(&hlds[tid][0]);
                const int m = 32 * hf + tid;
                unsigned long long* dst = reinterpret_cast<unsigned long long*>(
                    hout2 + (((size_t)(m >> 4) * 32 + (g >> 2)) * 64 + (g & 3) * 16 + (m & 15)) * 8);
                __hip_atomic_store(dst,     cv.u[0], __ATOMIC_RELAXED, __HIP_MEMORY_SCOPE_AGENT);
                __hip_atomic_store(dst + 1, cv.u[1], __ATOMIC_RELAXED, __HIP_MEMORY_SCOPE_AGENT);
            }
            if (w == 0)
                asm volatile("s_waitcnt vmcnt(0)" ::: "memory");
            if (tid == 0)
                __hip_atomic_store(&done[g * 16], (unsigned)(t + 1),
                                   __ATOMIC_RELAXED, __HIP_MEMORY_SCOPE_AGENT);
            if (g == 0 && tid < 64) {
                const unsigned tgt = (unsigned)(t + 1);
                unsigned v0 = 0, v1 = 0;
                while (1) {
                    if (v0 < tgt)
                        v0 = __hip_atomic_load(&done[tid * 16], __ATOMIC_RELAXED,
                                               __HIP_MEMORY_SCOPE_AGENT);
                    if (v1 < tgt)
                        v1 = __hip_atomic_load(&done[(tid + 64) * 16], __ATOMIC_RELAXED,
                                               __HIP_MEMORY_SCOPE_AGENT);
                    if (__all((v0 >= tgt) && (v1 >= tgt))) break;
                    __builtin_amdgcn_s_sleep(1);
                }
                if (tid < 16)
                    __hip_atomic_store(&go_own[tid * 16], tgt, __ATOMIC_RELAXED,
                                       __HIP_MEMORY_SCOPE_AGENT);
            }
        }
    }
}

__global__ __launch_bounds__(256) void softmax_rows(const float* __restrict__ logits,
                                                    float* __restrict__ out) {
    __shared__ float red[256];
    int rr = blockIdx.x, tid = threadIdx.x;
    const float* L = logits + (size_t)rr * VV;
    float m = -1e30f;
    for (int i = tid; i < VV; i += 256) m = fmaxf(m, L[i]);
    red[tid] = m; __syncthreads();
    for (int s = 128; s > 0; s >>= 1) { if (tid < s) red[tid] = fmaxf(red[tid], red[tid + s]); __syncthreads(); }
    m = red[0]; __syncthreads();
    float sum = 0.f;
    for (int i = tid; i < VV; i += 256) sum += expf(L[i] - m);
    red[tid] = sum; __syncthreads();
    for (int s = 128; s > 0; s >>= 1) { if (tid < s) red[tid] += red[tid + s]; __syncthreads(); }
    float inv = 1.f / red[0];
    for (int i = tid; i < VV; i += 256) out[(size_t)rr * VV + i] = expf(L[i] - m) * inv;
}

extern "C" void kernel_launch(void* const* d_in, const int* in_sizes, int n_in,
                              void* d_out, int out_size, void* d_ws, size_t ws_size,
                              hipStream_t stream) {
    const int*   x    = (const int*)  d_in[0];
    const float* tab  = (const float*)d_in[1];
    const float* Wx0  = (const float*)d_in[2];
    const float* Wh0  = (const float*)d_in[3];
    const float* b0   = (const float*)d_in[4];
    const float* Wx1  = (const float*)d_in[5];
    const float* Wh1  = (const float*)d_in[6];
    const float* b1   = (const float*)d_in[7];
    const float* Wout = (const float*)d_in[8];
    const float* bout = (const float*)d_in[9];
    float* out = (float*)d_out;

    // ---- workspace layout (ushort units); all segments 16B-aligned ----
    unsigned short* ws    = (unsigned short*)d_ws;
    unsigned short* embA  = ws;                    // 16,777,216
    unsigned short* wx0p  = embA  + 16777216;      //  2,097,152 (pack_whk KT=16)
    unsigned short* wh0p  = wx0p  + 2097152;       //  4,194,304 (pack_whk KT=32)
    unsigned short* wx1p  = wh0p  + 4194304;       //  4,194,304 (pack_whk KT=32)
    unsigned short* wh1p  = wx1p  + 4194304;       //  4,194,304 (pack_whk KT=32)
    unsigned short* woutp = wh1p  + 4194304;       // 32,768,000
    unsigned short* hb0   = woutp + 32768000;      // 65,536  (h1, even t out)
    unsigned short* hb1   = hb0   + 65536;         // 65,536  (h1, odd t out)
    unsigned short* hb2   = hb1   + 65536;         // 65,536  (h2)
    unsigned short* hb3   = hb2   + 65536;         // 65,536  (h2)
    float* logits = (float*)(hb3 + 65536);         // 2,048,000 f32
    unsigned int* flags = (unsigned int*)(logits + 2048000);  // 8192 done + 1024 go
    // total ~137 MB

    // ---- weight packing ----
    pack_whk<<<4096, 64, 0, stream>>>(Wx0, wx0p, 16);
    pack_whk<<<8192, 64, 0, stream>>>(Wh0, wh0p, 32);
    pack_whk<<<8192, 64, 0, stream>>>(Wx1, wx1p, 32);
    pack_whk<<<8192, 64, 0, stream>>>(Wh1, wh1p, 32);
    pack_b <<<2000 * 32, 64, 0, stream>>>(Wout, woutp, 32, VV);

    // ---- h0 + flag init ----
    zero_init<<<64, 256, 0, stream>>>(hb0, hb2, flags);

    // ---- embedding (packed-A form; consumed on the fly by layer 0) ----
    embed_pack<<<32768, 64, 0, stream>>>(x, tab, embA);

    // ---- fused two-layer recurrence (persistent cooperative, 512 blocks) ----
    {
        const unsigned short* a0 = embA; const unsigned short* a1 = wx0p;
        const unsigned short* a2 = wh0p; const unsigned short* a3 = wh1p;
        const unsigned short* a4 = wx1p;
        const float* a5 = b0; const float* a6 = b1;
        unsigned short *a7 = hb0, *a8 = hb1, *a9 = hb2, *a10 = hb3;
        unsigned int* a11 = flags;
        void* args[] = {&a0, &a1, &a2, &a3, &a4, &a5, &a6, &a7, &a8, &a9, &a10, &a11};
        hipLaunchCooperativeKernel((const void*)lstm_fused, dim3(512), dim3(256),
                                   args, 0, stream);
    }
    // t=511 (odd) writes layer-1 h into hb2

    // ---- logits (last timestep) + softmax ----
    gemm_bias<<<dim3(VV / 64, 1), 256, 0, stream>>>(hb2, woutp, bout, logits, VV, HH / 32);
    softmax_rows<<<64, 256, 0, stream>>>(logits, out);
}